// Round 10
// baseline (736.392 us; speedup 1.0000x reference)
//
#include <hip/hip_runtime.h>

// Capsule routing, B=64 R=2048 C=32 O=32 I=16, 3 routing iters.
// u_hat never materialized; recomputed per pass. Logit telescoping:
// b1 = u.v1 ; b2 = u.(v1+v2) -> no [B,R,C] logit buffer.
//
// R10 = R9 + latency pipelining. R9 was stall-bound (VALU issue ~84
// slots/body vs ~24 ideal; HBM 2.9%): per-body serial chain
// ds_read(120cyc) -> 8-deep dot2 chain -> fma, no cross-body overlap.
// Fixes: (1) x distance-2 prefetch (xbuf[2], ds_read for body b+2 issued
// during body b, carried across rr groups); (2) u0/u1 split into 2 partial
// accumulators (chain depth 8->4). Kept: packed fp16 dot2 (v_dot2_f32_f16),
// fp16 W stream (L3-resident), XCD swizzle, W ping-pong prefetch,
// fully-unrolled b-loop, __launch_bounds__(512,2) (R6 lesson: bound=4
// clamps to 64 VGPR and spills 700 MB).

#define Bn 64
#define Rn 2048
#define Cn 32
#define On 32
#define In 16
#define RC 32            // r per upass block
#define NRC (Rn / RC)    // 64 r-chunks
#define GB 8             // b per upass block
#define NBG (Bn / GB)    // 8 b-groups

typedef _Float16 half2v __attribute__((ext_vector_type(2)));

#if defined(__has_builtin)
#if __has_builtin(__builtin_amdgcn_fdot2)
#define FDOT2(a, b, c) __builtin_amdgcn_fdot2((a), (b), (c), false)
#endif
#endif
#ifndef FDOT2
#define FDOT2(a, b, c) fmaf((float)(a).x, (float)(b).x, \
                        fmaf((float)(a).y, (float)(b).y, (c)))
#endif

// W fp32 [2048,32,32,16] -> fp16 same layout. 8 elements/thread, vectorized.
__global__ __launch_bounds__(256)
void wconv(const float* __restrict__ W, _Float16* __restrict__ Wh) {
    const size_t i = ((size_t)blockIdx.x * 256 + threadIdx.x) * 8;
    const float4 a = *(const float4*)(W + i);
    const float4 b = *(const float4*)(W + i + 4);
    union { _Float16 h[8]; uint4 u; } pk;
    pk.h[0] = (_Float16)a.x; pk.h[1] = (_Float16)a.y;
    pk.h[2] = (_Float16)a.z; pk.h[3] = (_Float16)a.w;
    pk.h[4] = (_Float16)b.x; pk.h[5] = (_Float16)b.y;
    pk.h[6] = (_Float16)b.z; pk.h[7] = (_Float16)b.w;
    *(uint4*)(Wh + i) = pk.u;
}

// s_part layout: [NRC][Bn][1024] floats; thread slot = float2 at index tid.
// Thread map (512 thr): w=tid>>6, lane=tid&63, c=lane&31, oh=lane>>5,
// o = 4*w + 2*oh + {0,1}.

template <int PHASE>
__global__ __launch_bounds__(512, 2)   // bound=2: do NOT raise (R6 lesson)
void upass(const float* __restrict__ x, const _Float16* __restrict__ Wh,
           const float* __restrict__ vroute, float* __restrict__ s_part) {
    const int tid   = threadIdx.x;
    const int w     = tid >> 6;
    const int lane  = tid & 63;
    const int c     = lane & 31;
    const int oh    = lane >> 5;
    const int obase = (w << 2) + (oh << 1);

    // XCD swizzle: the 8 bg-blocks of one rc share blockIdx mod 8 -> same XCD.
    const int L  = blockIdx.x;
    const int bg = (L >> 3) & 7;
    const int rc = (L & 7) | ((L >> 6) << 3);   // [0,64)
    const int b0 = bg * GB;

    __shared__ __attribute__((aligned(16))) _Float16 xs[GB * RC * In]; // 8 KB
    __shared__ float lds_l[2][256];    // logit o-partials, ping-pong on b&1

    // cooperative x preload + fp32->fp16: b = tid>>6 owns its row chunk
    {
        const int bb = tid >> 6, j = tid & 63;
        const float4* src = (const float4*)(x +
                            (size_t)(b0 + bb) * (Rn * In) + (size_t)rc * (RC * In));
        _Float16* dsth = xs + bb * (RC * In);
        const float4 a0 = src[j];
        const float4 a1 = src[j + 64];
        union { _Float16 h[4]; uint2 u; } p0, p1;
        p0.h[0] = (_Float16)a0.x; p0.h[1] = (_Float16)a0.y;
        p0.h[2] = (_Float16)a0.z; p0.h[3] = (_Float16)a0.w;
        p1.h[0] = (_Float16)a1.x; p1.h[1] = (_Float16)a1.y;
        p1.h[2] = (_Float16)a1.z; p1.h[3] = (_Float16)a1.w;
        *(uint2*)(dsth + 4 * j)        = p0.u;
        *(uint2*)(dsth + 4 * (j + 64)) = p1.u;
    }

    float2 vr[GB];
    if (PHASE > 0) {
#pragma unroll
        for (int b = 0; b < GB; ++b)
            vr[b] = *(const float2*)(vroute +
                     ((size_t)(b0 + b) * Cn + c) * On + obase);
    }

    float sacc0[GB], sacc1[GB];
#pragma unroll
    for (int b = 0; b < GB; ++b) { sacc0[b] = 0.f; sacc1[b] = 0.f; }

    __syncthreads();   // xs ready

    // W fp16: thread slice = [r, c, obase..+1, 0:16] = 32 halfs = 4 uint4.
    // per-r stride = Cn*On*In/8 = 2048 uint4.
    const uint4* Wb = (const uint4*)Wh +
                      ((size_t)((rc * RC) * Cn + c) * On + obase) * 2;

    // x distance-2 pipeline: xbuf holds bodies b and b+1; prefetch b+2
    // during body b. Carried across rr groups (wraps into rr+1).
    uint4 xbuf[2][2];
    xbuf[0][0] = *(const uint4*)(xs + 0 * In);
    xbuf[0][1] = *(const uint4*)(xs + 0 * In + 8);
    xbuf[1][0] = *(const uint4*)(xs + RC * In);
    xbuf[1][1] = *(const uint4*)(xs + RC * In + 8);

    auto body = [&](int rr, const uint4 (&wst)[4]) {
        const half2v* wh = (const half2v*)&wst[0];   // [0..7]=o0, [8..15]=o1
#pragma unroll
        for (int b = 0; b < GB; ++b) {
            // prefetch body b+2 (wraps to next rr; at rr=RC-1 the wrap reads
            // in-array garbage that is never consumed)
            const int pb  = b + 2;
            const int pbb = pb & 7;
            const int prr = rr + (pb >> 3);
            const uint4 nx0 = *(const uint4*)(xs + (pbb * RC + prr) * In);
            const uint4 nx1 = *(const uint4*)(xs + (pbb * RC + prr) * In + 8);

            const half2v* xh = (const half2v*)&xbuf[b & 1][0];  // 8 half2
            float u0a = 0.f, u0b = 0.f, u1a = 0.f, u1b = 0.f;
#pragma unroll
            for (int j = 0; j < 4; ++j) {
                u0a = FDOT2(wh[j],     xh[j], u0a);
                u1a = FDOT2(wh[8 + j], xh[j], u1a);
            }
#pragma unroll
            for (int j = 4; j < 8; ++j) {
                u0b = FDOT2(wh[j],     xh[j], u0b);
                u1b = FDOT2(wh[8 + j], xh[j], u1b);
            }
            const float u0 = u0a + u0b;
            const float u1 = u1a + u1b;

            float weight;
            if (PHASE == 0) {
                weight = 0.03125f;   // softmax(0) uniform = 1/32
            } else {
                float lp = u0 * vr[b].x + u1 * vr[b].y;  // 2 o's
                lp += __shfl_xor(lp, 32, 64);            // + oh partner
                if (lane < 32) lds_l[b & 1][w * 32 + c] = lp;
                __syncthreads();                          // 1 barrier/(rr,b)
                float l = 0.f;
#pragma unroll
                for (int k = 0; k < 8; ++k) l += lds_l[b & 1][k * 32 + c];
                // softmax over c (lanes 0..31 <-> c, dup upper half);
                // no max-subtract: |l| <~ 30 << 88 for N(0,1) inputs.
                const float e = __expf(l);
                float ssum = e;
#pragma unroll
                for (int d = 1; d < 32; d <<= 1)
                    ssum += __shfl_xor(ssum, d, 64);
                weight = e * __builtin_amdgcn_rcpf(ssum);
            }
            sacc0[b] = fmaf(weight, u0, sacc0[b]);
            sacc1[b] = fmaf(weight, u1, sacc1[b]);
            xbuf[b & 1][0] = nx0;
            xbuf[b & 1][1] = nx1;
        }
    };

    uint4 wa[4], wb[4];
#pragma unroll
    for (int j = 0; j < 4; ++j) wa[j] = Wb[j];

    for (int rr = 0; rr < RC; rr += 2) {
#pragma unroll
        for (int j = 0; j < 4; ++j) wb[j] = Wb[(size_t)(rr + 1) * 2048 + j];
        body(rr, wa);
        if (rr + 2 < RC) {
#pragma unroll
            for (int j = 0; j < 4; ++j) wa[j] = Wb[(size_t)(rr + 2) * 2048 + j];
        }
        body(rr + 1, wb);
    }

#pragma unroll
    for (int b = 0; b < GB; ++b)
        ((float2*)s_part)[((size_t)rc * Bn + (b0 + b)) * 512 + tid] =
            make_float2(sacc0[b], sacc1[b]);
}

// stage 1 reduce: 64 rc-partials -> 8 group-partials. grid (8, 64)
__global__ __launch_bounds__(256)
void reduce1(const float* __restrict__ s_part, float* __restrict__ s2) {
    const int g = blockIdx.x;   // [0,8)
    const int b = blockIdx.y;   // [0,64)
    const int t = threadIdx.x;
    float4 acc = make_float4(0.f, 0.f, 0.f, 0.f);
#pragma unroll
    for (int j = 0; j < 8; ++j) {
        float4 v = ((const float4*)s_part)[((size_t)(g * 8 + j) * Bn + b) * 256 + t];
        acc.x += v.x; acc.y += v.y; acc.z += v.z; acc.w += v.w;
    }
    ((float4*)s2)[((size_t)g * Bn + b) * 256 + t] = acc;
}

// stage 2: finish reduce, squash, write v ([b,c,o]); optional vsum = v+vprev.
// 512 threads, same (c, 2 o) slot map as upass.
__global__ __launch_bounds__(512)
void squash2(const float* __restrict__ s2, float scale,
             float* __restrict__ vout, const float* __restrict__ vprev,
             float* __restrict__ vsum_out) {
    const int b     = blockIdx.x;   // [0,64)
    const int t     = threadIdx.x;
    const int w     = t >> 6;
    const int lane  = t & 63;
    const int c     = lane & 31;
    const int oh    = lane >> 5;
    const int obase = (w << 2) + (oh << 1);
    __shared__ float lds_n[256];

    float2 acc = make_float2(0.f, 0.f);
#pragma unroll
    for (int g = 0; g < 8; ++g) {
        float2 v = ((const float2*)s2)[((size_t)g * Bn + b) * 512 + t];
        acc.x += v.x; acc.y += v.y;
    }
    acc.x *= scale; acc.y *= scale;

    float n2p = acc.x * acc.x + acc.y * acc.y;
    n2p += __shfl_xor(n2p, 32, 64);
    if (lane < 32) lds_n[w * 32 + c] = n2p;
    __syncthreads();
    float n2 = 0.f;
#pragma unroll
    for (int k = 0; k < 8; ++k) n2 += lds_n[k * 32 + c];
    const float norm = sqrtf(n2);
    const float f = (n2 / (1.f + n2)) / (norm + 1e-8f);

    float2 vv = make_float2(acc.x * f, acc.y * f);
    const size_t oidx = (size_t)b * 1024 + (size_t)c * 32 + obase;
    if (vout) *(float2*)(vout + oidx) = vv;
    if (vsum_out) {
        float2 vp = *(const float2*)(vprev + oidx);
        *(float2*)(vsum_out + oidx) = make_float2(vv.x + vp.x, vv.y + vp.y);
    }
}

extern "C" void kernel_launch(void* const* d_in, const int* in_sizes, int n_in,
                              void* d_out, int out_size, void* d_ws, size_t ws_size,
                              hipStream_t stream) {
    const float* x = (const float*)d_in[0];   // [64,2048,16]
    const float* W = (const float*)d_in[1];   // [2048,32,32,16]
    float* out = (float*)d_out;               // [64,32,32]

    char* ws = (char*)d_ws;
    _Float16* Wh  = (_Float16*)ws;                             // 64 MB
    float* s_part = (float*)(ws + (size_t)67108864);           // 16 MB
    float* s2     = (float*)(ws + (size_t)67108864 + 16777216);            // 2 MB
    float* v1     = (float*)(ws + (size_t)67108864 + 16777216 + 2097152);  // 256 KB
    float* v12    = (float*)(ws + (size_t)67108864 + 16777216 + 2097152 + 262144);

    const int ublocks = NBG * NRC;   // 512
    dim3 rg(8, Bn);                  // (8, 64)

    // W -> fp16 (33.5M elements, 8/thread)
    wconv<<<16384, 256, 0, stream>>>(W, Wh);

    // iter 1: uniform 1/32 applied INSIDE upass<0> (scale=1 in squash)
    upass<0><<<ublocks, 512, 0, stream>>>(x, Wh, nullptr, s_part);
    reduce1<<<rg, 256, 0, stream>>>(s_part, s2);
    squash2<<<Bn, 512, 0, stream>>>(s2, 1.0f, v1, nullptr, nullptr);

    // iter 2: logits = u.v1 ; keep only v12 = v1+v2
    upass<1><<<ublocks, 512, 0, stream>>>(x, Wh, v1, s_part);
    reduce1<<<rg, 256, 0, stream>>>(s_part, s2);
    squash2<<<Bn, 512, 0, stream>>>(s2, 1.f, nullptr, v1, v12);

    // iter 3: logits = u.(v1+v2) ; output v3
    upass<2><<<ublocks, 512, 0, stream>>>(x, Wh, v12, s_part);
    reduce1<<<rg, 256, 0, stream>>>(s_part, s2);
    squash2<<<Bn, 512, 0, stream>>>(s2, 1.f, out, nullptr, nullptr);
}

// Round 11
// 316.297 us; speedup vs baseline: 2.3282x; 2.3282x over previous
//
#include <hip/hip_runtime.h>

// Capsule routing, B=64 R=2048 C=32 O=32 I=16, 3 routing iters.
// u_hat never materialized; recomputed per pass. Logit telescoping:
// b1 = u.v1 ; b2 = u.(v1+v2).
//
// R11: MFMA rewrite. R9/R10 plateaued at 240 us/pass (VALU-issue soup +
// latency stalls; source pipelining neutral => structural ceiling).
// Per r: u[co][b] = W[r](1024x16) * x(16x64) via v_mfma_f32_16x16x16_f16,
// one MFMA per 16x16 tile (8192 FLOP/instr, ~32x fewer instrs than dot2).
// Wave w owns c=4w..4w+3 (8 m-tiles), block n-dim = 16 b's.
// Fragment layouts (cdna_hip_programming.md section 3):
//   A[m=lane&15][k=quad*4+j]  -> 8B coalesced global load from fp16 W
//   B[k=quad*4+j][n=lane&15]  -> 8B LDS read from fp16-staged x
//   D[row=quad*4+reg][col=lane&15], regs = 4 contiguous co -> float4 stores
// Phase 0: s accumulated in MFMA C across r (no barrier in loop).
// Phase 1/2: D per r; l=sum_o u*v via ds_read_b128(v)+4fma per tile;
// softmax = per-wave exp-sums + 16-float LDS exchange, 1 barrier/r
// (double-buffered parity). No max-subtract (|l|<~30, validated R4-R10).
// __launch_bounds__(512,2) (R6 lesson: bound=4 => 64-VGPR clamp + spills).

#define Bn 64
#define Rn 2048
#define Cn 32
#define On 32
#define In 16
#define RCH 16            // r per block
#define NRC2 (Rn / RCH)   // 128 r-chunks
#define NG 4              // b-groups of 16

typedef _Float16 half4v __attribute__((ext_vector_type(4)));
typedef float floatx4 __attribute__((ext_vector_type(4)));

// W fp32 [2048,32,32,16] -> fp16 same layout. 8 elements/thread.
__global__ __launch_bounds__(256)
void wconv(const float* __restrict__ W, _Float16* __restrict__ Wh) {
    const size_t i = ((size_t)blockIdx.x * 256 + threadIdx.x) * 8;
    const float4 a = *(const float4*)(W + i);
    const float4 b = *(const float4*)(W + i + 4);
    union { _Float16 h[8]; uint4 u; } pk;
    pk.h[0] = (_Float16)a.x; pk.h[1] = (_Float16)a.y;
    pk.h[2] = (_Float16)a.z; pk.h[3] = (_Float16)a.w;
    pk.h[4] = (_Float16)b.x; pk.h[5] = (_Float16)b.y;
    pk.h[6] = (_Float16)b.z; pk.h[7] = (_Float16)b.w;
    *(uint4*)(Wh + i) = pk.u;
}

// s_part: [NRC2][64 b][1024 co] f32 (32 MB)
template <int PHASE>
__global__ __launch_bounds__(512, 2)
void upass(const float* __restrict__ x, const _Float16* __restrict__ Wh,
           const float* __restrict__ vroute, float* __restrict__ s_part) {
    const int tid  = threadIdx.x;
    const int w    = tid >> 6;      // wave 0..7 -> c = 4w..4w+3
    const int lane = tid & 63;
    const int q    = lane >> 4;     // quad
    const int bl   = lane & 15;     // A row / B col / D col

    // XCD swizzle: 4 bg-blocks of one rc share blockIdx mod 8 -> same XCD.
    const int L  = blockIdx.x;
    const int bg = (L >> 3) & 3;
    const int rc = (L & 7) | ((L >> 5) << 3);   // [0,128)
    const int b0 = bg * 16;

    // xs[rr][bb][20] halfs (pad 16->20: 8B-aligned b64, conflict-free)
    __shared__ __attribute__((aligned(16))) _Float16 xs[RCH * 16 * 20];
    // vs[bb][1028] f32 (pad 1024->1028 breaks 16-way conflict on b128)
    __shared__ __attribute__((aligned(16))) float vs[(PHASE > 0) ? 16 * 1028 : 4];
    __shared__ __attribute__((aligned(16))) float sums[2][16][8];

    // ---- preload x chunk -> fp16 LDS: 16 r x 16 b x 16 i ----
#pragma unroll
    for (int k = 0; k < 2; ++k) {
        const int u  = tid + k * 512;
        const int rr = u >> 6, bb = (u >> 2) & 15, iq = u & 3;
        const float4 xv = *(const float4*)(x + (size_t)(b0 + bb) * (Rn * In) +
                                           (size_t)(rc * RCH + rr) * In + iq * 4);
        union { _Float16 h[4]; uint2 u2; } p;
        p.h[0] = (_Float16)xv.x; p.h[1] = (_Float16)xv.y;
        p.h[2] = (_Float16)xv.z; p.h[3] = (_Float16)xv.w;
        *(uint2*)(xs + (rr * 16 + bb) * 20 + iq * 4) = p.u2;
    }
    // ---- preload v slice (16 b x 1024) fp32 ----
    if constexpr (PHASE > 0) {
#pragma unroll
        for (int k = 0; k < 8; ++k) {
            const int u = tid + k * 512;
            const int bb = u >> 8, off = (u & 255) * 4;
            const float4 vv = *(const float4*)(vroute + (size_t)(b0 + bb) * 1024 + off);
            *(float4*)(vs + bb * 1028 + off) = vv;
        }
    }
    __syncthreads();

    floatx4 accS[8];
#pragma unroll
    for (int m = 0; m < 8; ++m) accS[m] = (floatx4){0.f, 0.f, 0.f, 0.f};

    for (int rr = 0; rr < RCH; ++rr) {
        const int r = rc * RCH + rr;
        // A: W[r, co = w*128 + m*16 + bl, i = 4q .. 4q+3]
        const _Float16* Wr = Wh + ((size_t)r * 1024 + w * 128 + bl) * 16 + 4 * q;
        half4v a[8];
#pragma unroll
        for (int m = 0; m < 8; ++m) a[m] = *(const half4v*)(Wr + m * 256);
        // B: x[b = bl, r, i = 4q .. 4q+3]
        const half4v bf = *(const half4v*)(xs + (rr * 16 + bl) * 20 + 4 * q);

        if constexpr (PHASE == 0) {
#pragma unroll
            for (int m = 0; m < 8; ++m)
                accS[m] = __builtin_amdgcn_mfma_f32_16x16x16f16(a[m], bf, accS[m], 0, 0, 0);
        } else {
            floatx4 D[8];
#pragma unroll
            for (int m = 0; m < 8; ++m)
                D[m] = __builtin_amdgcn_mfma_f32_16x16x16f16(
                           a[m], bf, (floatx4){0.f, 0.f, 0.f, 0.f}, 0, 0, 0);

            // logits l[b,c] = sum_o u*v ; tile 2t: o=4q+reg, 2t+1: o=16+4q+reg
            float e[4], se = 0.f;
#pragma unroll
            for (int t = 0; t < 4; ++t) {
                const int ct = w * 4 + t;
                const float* vp = vs + bl * 1028 + ct * 32 + 4 * q;
                const floatx4 v0 = *(const floatx4*)(vp);
                const floatx4 v1 = *(const floatx4*)(vp + 16);
                float lp = D[2*t].x * v0.x + D[2*t].y * v0.y +
                           D[2*t].z * v0.z + D[2*t].w * v0.w +
                           D[2*t+1].x * v1.x + D[2*t+1].y * v1.y +
                           D[2*t+1].z * v1.z + D[2*t+1].w * v1.w;
                lp += __shfl_xor(lp, 16, 64);   // sum over quads (o coverage)
                lp += __shfl_xor(lp, 32, 64);
                e[t] = __expf(lp);              // no max-subtract (|l| small)
                se += e[t];
            }
            if (lane < 16) sums[rr & 1][bl][w] = se;
            __syncthreads();                     // 1 barrier per r
            const floatx4 s0 = *(const floatx4*)(&sums[rr & 1][bl][0]);
            const floatx4 s1 = *(const floatx4*)(&sums[rr & 1][bl][4]);
            const float tot = s0.x + s0.y + s0.z + s0.w +
                              s1.x + s1.y + s1.z + s1.w;
            const float winv = __builtin_amdgcn_rcpf(tot);
#pragma unroll
            for (int t = 0; t < 4; ++t) {
                const float wt = e[t] * winv;
                accS[2*t]   += wt * D[2*t];
                accS[2*t+1] += wt * D[2*t+1];
            }
        }
    }

    // store: co = w*128 + m*16 + 4q + reg (regs contiguous -> float4)
    const size_t sb = (((size_t)rc * 64 + b0 + bl)) * 1024 + w * 128 + 4 * q;
#pragma unroll
    for (int m = 0; m < 8; ++m)
        *(floatx4*)(s_part + sb + m * 16) = accS[m];
}

// sum 128 rc-partials -> s2[64][1024]
__global__ __launch_bounds__(256)
void reduce_all(const float* __restrict__ sp, float* __restrict__ s2) {
    const int b = blockIdx.x, t = threadIdx.x;
    floatx4 acc = (floatx4){0.f, 0.f, 0.f, 0.f};
    for (int k = 0; k < NRC2; ++k)
        acc += *(const floatx4*)(sp + ((size_t)k * 64 + b) * 1024 + t * 4);
    *(floatx4*)(s2 + (size_t)b * 1024 + t * 4) = acc;
}

// squash (scale applied BEFORE the nonlinearity); optional vsum = v + vprev
__global__ __launch_bounds__(256)
void squash_v(const float* __restrict__ s2, float scale,
              float* __restrict__ vout, const float* __restrict__ vprev,
              float* __restrict__ vsum) {
    const int b = blockIdx.x, t = threadIdx.x;
    const int c = t >> 3, j = t & 7;
    floatx4 s = *(const floatx4*)(s2 + (size_t)b * 1024 + c * 32 + j * 4);
    s *= scale;
    float n2 = s.x * s.x + s.y * s.y + s.z * s.z + s.w * s.w;
    n2 += __shfl_xor(n2, 1, 64);
    n2 += __shfl_xor(n2, 2, 64);
    n2 += __shfl_xor(n2, 4, 64);
    const float norm = sqrtf(n2);
    const float f = (n2 / (1.f + n2)) / (norm + 1e-8f);
    const floatx4 vv = s * f;
    const size_t o = (size_t)b * 1024 + c * 32 + j * 4;
    if (vout) *(floatx4*)(vout + o) = vv;
    if (vsum) {
        const floatx4 vp = *(const floatx4*)(vprev + o);
        *(floatx4*)(vsum + o) = vv + vp;
    }
}

extern "C" void kernel_launch(void* const* d_in, const int* in_sizes, int n_in,
                              void* d_out, int out_size, void* d_ws, size_t ws_size,
                              hipStream_t stream) {
    const float* x = (const float*)d_in[0];   // [64,2048,16]
    const float* W = (const float*)d_in[1];   // [2048,32,32,16]
    float* out = (float*)d_out;               // [64,32,32]

    char* ws = (char*)d_ws;
    _Float16* Wh  = (_Float16*)ws;                              // 64 MB
    float* s_part = (float*)(ws + (size_t)67108864);            // 32 MB
    float* s2     = (float*)(ws + (size_t)67108864 + 33554432);             // 256 KB
    float* v1     = (float*)(ws + (size_t)67108864 + 33554432 + 262144);    // 256 KB
    float* v12    = (float*)(ws + (size_t)67108864 + 33554432 + 524288);    // 256 KB

    const int ublocks = NG * NRC2;   // 512

    wconv<<<16384, 256, 0, stream>>>(W, Wh);

    // iter 1: uniform coefficients; 1/32 applied as squash pre-scale
    upass<0><<<ublocks, 512, 0, stream>>>(x, Wh, nullptr, s_part);
    reduce_all<<<Bn, 256, 0, stream>>>(s_part, s2);
    squash_v<<<Bn, 256, 0, stream>>>(s2, 1.f / 32.f, v1, nullptr, nullptr);

    // iter 2: logits = u.v1 ; keep only v12 = v1 + v2
    upass<1><<<ublocks, 512, 0, stream>>>(x, Wh, v1, s_part);
    reduce_all<<<Bn, 256, 0, stream>>>(s_part, s2);
    squash_v<<<Bn, 256, 0, stream>>>(s2, 1.f, nullptr, v1, v12);

    // iter 3: logits = u.(v1+v2) ; output v3
    upass<2><<<ublocks, 512, 0, stream>>>(x, Wh, v12, s_part);
    reduce_all<<<Bn, 256, 0, stream>>>(s_part, s2);
    squash_v<<<Bn, 256, 0, stream>>>(s2, 1.f, out, nullptr, nullptr);
}